// Round 9
// baseline (120.419 us; speedup 1.0000x reference)
//
#include <hip/hip_runtime.h>
#include <hip/hip_bf16.h>

#define NROWS 2048
#define HH 72    // LDS row stride in halves: 144 B, 16B-aligned

typedef __attribute__((ext_vector_type(4))) float f32x4;
typedef _Float16 f16x2 __attribute__((ext_vector_type(2)));
typedef _Float16 f16x4 __attribute__((ext_vector_type(4)));
typedef _Float16 f16x8 __attribute__((ext_vector_type(8)));
typedef __fp16 fp16x2_raw __attribute__((ext_vector_type(2)));

union H8 { f16x8 v; f16x2 h2[4]; };

static __device__ __forceinline__ f32x4 vmax0(f32x4 a) {
    return __builtin_elementwise_max(a, (f32x4)0.f);
}
static __device__ __forceinline__ f16x8 hmax0(f16x8 a) {
    return __builtin_elementwise_max(a, (f16x8)(_Float16)0.f);
}
// v_cvt_pkrtz_f16_f32: returns __fp16x2; bit-cast to our _Float16x2
static __device__ __forceinline__ f16x2 pkrtz(float a, float b) {
    union { fp16x2_raw r; f16x2 f; } c;
    c.r = __builtin_amdgcn_cvt_pkrtz(a, b);
    return c.f;
}

// Workspace layout (floats):
//   TI : ws[0    .. 2688)  42 rows x 64 (i-side: subj 0-15, rel 16-24, obj 25-40, const 41)
//   TJ : ws[2688 .. 5376)  42 rows x 64 (j-side)
#define TJ_OFF  2688

// ---------------- Kernel T: fused e-table + H-table ----------------
__global__ __launch_bounds__(256) void tab_kernel(
    const float* __restrict__ subj_table, const float* __restrict__ rel_table,
    const float* __restrict__ obj_table,
    const float* __restrict__ proj_w, const float* __restrict__ proj_b,
    const float* __restrict__ w1, const float* __restrict__ b1,
    float* __restrict__ ws)
{
    __shared__ float et[64];
    const int b = blockIdx.x;            // 0..83
    const int side = b & 1;
    const int r = b >> 1;                // 0..41
    const int tid = threadIdx.x;
    const int lane = tid & 63;
    const int w = tid >> 6;

    // ---- stage 1: ET row r ----
    if (r == 41) {
        if (tid < 64) et[tid] = proj_b[tid];
    } else {
        const float* src; int off;
        if (r < 16)      { src = subj_table + r * 64;        off = 0;   }
        else if (r < 25) { src = rel_table + (r - 16) * 64;  off = 64;  }
        else             { src = obj_table + (r - 25) * 64;  off = 128; }
        const float sv = src[lane];
        #pragma unroll
        for (int t = 0; t < 4; ++t) {
            const int d0 = w * 16 + t * 4;
            float p0 = sv * proj_w[(d0 + 0) * 192 + off + lane];
            float p1 = sv * proj_w[(d0 + 1) * 192 + off + lane];
            float p2 = sv * proj_w[(d0 + 2) * 192 + off + lane];
            float p3 = sv * proj_w[(d0 + 3) * 192 + off + lane];
            #pragma unroll
            for (int m = 1; m < 64; m <<= 1) {
                p0 += __shfl_xor(p0, m, 64);
                p1 += __shfl_xor(p1, m, 64);
                p2 += __shfl_xor(p2, m, 64);
                p3 += __shfl_xor(p3, m, 64);
            }
            if (lane == 0) {
                et[d0 + 0] = p0; et[d0 + 1] = p1;
                et[d0 + 2] = p2; et[d0 + 3] = p3;
            }
        }
    }
    __syncthreads();

    // ---- stage 2: H row ----
    float* dst = ws + (side ? TJ_OFF : 0);
    const float sv2 = et[lane];
    const int woff = side * 64;
    #pragma unroll
    for (int t = 0; t < 4; ++t) {
        const int d0 = w * 16 + t * 4;
        float p0 = sv2 * w1[(d0 + 0) * 128 + woff + lane];
        float p1 = sv2 * w1[(d0 + 1) * 128 + woff + lane];
        float p2 = sv2 * w1[(d0 + 2) * 128 + woff + lane];
        float p3 = sv2 * w1[(d0 + 3) * 128 + woff + lane];
        #pragma unroll
        for (int m = 1; m < 64; m <<= 1) {
            p0 += __shfl_xor(p0, m, 64);
            p1 += __shfl_xor(p1, m, 64);
            p2 += __shfl_xor(p2, m, 64);
            p3 += __shfl_xor(p3, m, 64);
        }
        if (lane == 0) {
            const bool cst = (side == 0) && (r == 41);
            dst[r * 64 + d0 + 0] = p0 + (cst ? b1[d0 + 0] : 0.f);
            dst[r * 64 + d0 + 1] = p1 + (cst ? b1[d0 + 1] : 0.f);
            dst[r * 64 + d0 + 2] = p2 + (cst ? b1[d0 + 2] : 0.f);
            dst[r * 64 + d0 + 3] = p3 + (cst ? b1[d0 + 3] : 0.f);
        }
    }
}

// ---------------- Kernel B: pairwise scores via fp16 MFMA ----------------
// 32x32 pair tile / block (4 waves). Inner loop: 2 ds_read_b128 + packed fp16
// add/max -> 4 MFMA (b2 enters as the C operand of the first) -> in-register
// w3 dot -> ONE fp16 LDS partial per lane. Deferred wave-local epilogue.
// launch_bounds(256,6): 6 blocks/CU (VGPR cap ~85 > our ~60, LDS 18432 B).
#define PH 72   // partial row stride in halves (144 B, 16B-aligned)

__global__ __launch_bounds__(256, 6) void pair_kernel(
    const int* __restrict__ subj_idx, const int* __restrict__ rel_idx,
    const int* __restrict__ obj_idx,
    const float* __restrict__ tab,
    const float* __restrict__ w2, const float* __restrict__ b2,
    const float* __restrict__ w3, const float* __restrict__ b3,
    float* __restrict__ out)
{
    const int bx = blockIdx.x, by = blockIdx.y;
    const int i0 = by * 32, j0 = bx * 32;
    const int tid = threadIdx.x;

    if (bx < by) {   // entire tile strictly below diagonal -> zeros
        const float4 z = {0.f, 0.f, 0.f, 0.f};
        ((float4*)(out + (size_t)(i0 + (tid >> 3)) * NROWS + j0))[tid & 7] = z;
        return;
    }

    __shared__ _Float16 hiL[32 * HH];        // 4608 B
    __shared__ _Float16 hjL[32 * HH];        // 4608 B
    __shared__ _Float16 part[4 * 16 * PH];   // 9216 B, per-wave slices

    const int lane = tid & 63;
    const int wid  = tid >> 6;
    const int col  = lane & 15;
    const int quad = lane >> 4;
    const int wj   = wid & 1;
    const int wi   = wid >> 1;

    // ---- fused gather: row = T[s] + T[16+r] + T[25+o] + T[41], fp32 -> fp16 LDS ----
    {
        const int rr = tid >> 3;             // 0..31
        const int cc = (tid & 7) * 8;        // halves / floats
        const int iR = i0 + rr, jR = j0 + rr;
        const int si = subj_idx[iR], ri = 16 + rel_idx[iR], oi = 25 + obj_idx[iR];
        const int sj = subj_idx[jR], rj = 16 + rel_idx[jR], oj = 25 + obj_idx[jR];
        const float* TI = tab;
        const float* TJ = tab + TJ_OFF;
        const f32x4 v0 = *(const f32x4*)(TI + si * 64 + cc)
                       + *(const f32x4*)(TI + ri * 64 + cc)
                       + *(const f32x4*)(TI + oi * 64 + cc)
                       + *(const f32x4*)(TI + 41 * 64 + cc);
        const f32x4 v1 = *(const f32x4*)(TI + si * 64 + cc + 4)
                       + *(const f32x4*)(TI + ri * 64 + cc + 4)
                       + *(const f32x4*)(TI + oi * 64 + cc + 4)
                       + *(const f32x4*)(TI + 41 * 64 + cc + 4);
        H8 hp;
        hp.h2[0] = pkrtz(v0[0], v0[1]); hp.h2[1] = pkrtz(v0[2], v0[3]);
        hp.h2[2] = pkrtz(v1[0], v1[1]); hp.h2[3] = pkrtz(v1[2], v1[3]);
        *(f16x8*)&hiL[rr * HH + cc] = hp.v;

        const f32x4 u0 = *(const f32x4*)(TJ + sj * 64 + cc)
                       + *(const f32x4*)(TJ + rj * 64 + cc)
                       + *(const f32x4*)(TJ + oj * 64 + cc)
                       + *(const f32x4*)(TJ + 41 * 64 + cc);
        const f32x4 u1 = *(const f32x4*)(TJ + sj * 64 + cc + 4)
                       + *(const f32x4*)(TJ + rj * 64 + cc + 4)
                       + *(const f32x4*)(TJ + oj * 64 + cc + 4)
                       + *(const f32x4*)(TJ + 41 * 64 + cc + 4);
        H8 hq;
        hq.h2[0] = pkrtz(u0[0], u0[1]); hq.h2[1] = pkrtz(u0[2], u0[3]);
        hq.h2[2] = pkrtz(u1[0], u1[1]); hq.h2[3] = pkrtz(u1[2], u1[3]);
        *(f16x8*)&hjL[rr * HH + cc] = hq.v;
    }

    // w2 A-frags (block-invariant): lane = channel ch*16+col, k = ks*32+quad*8+j
    H8 wf[2][2];
    #pragma unroll
    for (int ch = 0; ch < 2; ++ch)
        #pragma unroll
        for (int ks = 0; ks < 2; ++ks) {
            const f32x4* wr = (const f32x4*)(w2 + (ch * 16 + col) * 64 + ks * 32 + quad * 8);
            const f32x4 w0 = wr[0], w1v = wr[1];
            wf[ch][ks].h2[0] = pkrtz(w0[0], w0[1]);
            wf[ch][ks].h2[1] = pkrtz(w0[2], w0[3]);
            wf[ch][ks].h2[2] = pkrtz(w1v[0], w1v[1]);
            wf[ch][ks].h2[3] = pkrtz(w1v[2], w1v[3]);
        }
    // epilogue coefficients: lane's channels are quad*4+r (accA) / 16+quad*4+r (accB)
    const f32x4 b2A = *(const f32x4*)(b2 + quad * 4);
    const f32x4 b2B = *(const f32x4*)(b2 + 16 + quad * 4);
    const f32x4 w3A = *(const f32x4*)(w3 + quad * 4);
    const f32x4 w3B = *(const f32x4*)(w3 + 16 + quad * 4);
    const float b3v = b3[0];

    __syncthreads();

    // loop-invariant hj fragments (this wave's 16 j's; lane's j = wj*16+col)
    const int hjb = (wj * 16 + col) * HH + quad * 8;
    const f16x8 hj0 = *(const f16x8*)&hjL[hjb];        // ks=0
    const f16x8 hj1 = *(const f16x8*)&hjL[hjb + 32];   // ks=1

    _Float16* mypart = &part[wid * 16 * PH];

    #pragma unroll 8
    for (int it = 0; it < 16; ++it) {
        const int base = (wi * 16 + it) * HH + quad * 8;
        // hi broadcast reads (same addr across the 16 lanes of a quad)
        const f16x8 x0 = *(const f16x8*)&hiL[base];
        const f16x8 x1 = *(const f16x8*)&hiL[base + 32];

        // h = relu(hi + hj), all fp16 packed -> MFMA operand directly
        const f16x8 f0 = hmax0(x0 + hj0);
        const f16x8 f1 = hmax0(x1 + hj1);

        // b2 enters as the C operand of the first MFMA (no acc-init movs)
        f32x4 accA = __builtin_amdgcn_mfma_f32_16x16x32_f16(wf[0][0].v, f0, b2A, 0, 0, 0);
        accA       = __builtin_amdgcn_mfma_f32_16x16x32_f16(wf[0][1].v, f1, accA, 0, 0, 0);
        f32x4 accB = __builtin_amdgcn_mfma_f32_16x16x32_f16(wf[1][0].v, f0, b2B, 0, 0, 0);
        accB       = __builtin_amdgcn_mfma_f32_16x16x32_f16(wf[1][1].v, f1, accB, 0, 0, 0);

        // relu + w3 partial dot over this lane's 8 channels; one fp16 LDS partial
        const f32x4 ra = vmax0(accA);
        const f32x4 rb = vmax0(accB);
        const f32x4 t4 = ra * w3A + rb * w3B;
        mypart[it * PH + quad * 16 + col] =
            (_Float16)((t4[0] + t4[1]) + (t4[2] + t4[3]));
    }

    // ---- deferred wave-local epilogue (same-wave producer: no barrier) ----
    {
        const int sub = lane & 3;            // j-col group (4 cols each)
        const int itx = lane >> 2;           // 0..15 -> i row
        const _Float16* pr = &mypart[itx * PH + sub * 4];
        const f16x4 s4 = *(const f16x4*)(pr)
                       + *(const f16x4*)(pr + 16)
                       + *(const f16x4*)(pr + 32)
                       + *(const f16x4*)(pr + 48);
        const int i  = i0 + wi * 16 + itx;
        const int jb = j0 + wj * 16 + sub * 4;
        float4 o;
        o.x = (jb + 0 > i) ? 1.f / (1.f + __expf(-((float)s4[0] + b3v))) : 0.f;
        o.y = (jb + 1 > i) ? 1.f / (1.f + __expf(-((float)s4[1] + b3v))) : 0.f;
        o.z = (jb + 2 > i) ? 1.f / (1.f + __expf(-((float)s4[2] + b3v))) : 0.f;
        o.w = (jb + 3 > i) ? 1.f / (1.f + __expf(-((float)s4[3] + b3v))) : 0.f;
        *(float4*)(out + (size_t)i * NROWS + jb) = o;
    }
}

extern "C" void kernel_launch(void* const* d_in, const int* in_sizes, int n_in,
                              void* d_out, int out_size, void* d_ws, size_t ws_size,
                              hipStream_t stream) {
    const int*   subj_idx   = (const int*)d_in[0];
    const int*   rel_idx    = (const int*)d_in[1];
    const int*   obj_idx    = (const int*)d_in[2];
    const float* subj_table = (const float*)d_in[3];
    const float* rel_table  = (const float*)d_in[4];
    const float* obj_table  = (const float*)d_in[5];
    const float* proj_w     = (const float*)d_in[6];
    const float* proj_b     = (const float*)d_in[7];
    const float* w1         = (const float*)d_in[8];
    const float* b1         = (const float*)d_in[9];
    const float* w2         = (const float*)d_in[10];
    const float* b2         = (const float*)d_in[11];
    const float* w3         = (const float*)d_in[12];
    const float* b3         = (const float*)d_in[13];
    float* out = (float*)d_out;
    float* ws  = (float*)d_ws;

    tab_kernel<<<dim3(84), dim3(256), 0, stream>>>(
        subj_table, rel_table, obj_table, proj_w, proj_b, w1, b1, ws);

    pair_kernel<<<dim3(NROWS / 32, NROWS / 32), dim3(256), 0, stream>>>(
        subj_idx, rel_idx, obj_idx, ws, w2, b2, w3, b3, out);
}